// Round 12
// baseline (2563.851 us; speedup 1.0000x reference)
//
#include <hip/hip_runtime.h>
#include <hip/hip_bf16.h>
#include <math.h>

#define NB 32
#define NS 4096
#define ND 256
#define NHOP 10
#define EPSBN 1e-5f
#define NEG_SLOPE 0.01f

typedef _Float16 half8 __attribute__((ext_vector_type(8)));
typedef float floatx4 __attribute__((ext_vector_type(4)));

// ---------------- workspace layout (bytes) ----------------
static const size_t SZ_PAIR = (size_t)NB*NS*ND*2;            // 67,108,864 (ushort plane)
static const size_t OFF_HI0 = 0;
static const size_t OFF_LO0 = OFF_HI0 + SZ_PAIR;
static const size_t OFF_HI1 = OFF_LO0 + SZ_PAIR;
static const size_t OFF_LO1 = OFF_HI1 + SZ_PAIR;
static const size_t OFF_MP  = OFF_LO1 + SZ_PAIR;             // m_part [NB*32]
static const size_t OFF_LP  = OFF_MP  + (size_t)NB*32*4;     // l_part [NB*32]
static const size_t OFF_Q   = OFF_LP  + (size_t)NB*32*4;
static const size_t OFF_OP  = OFF_Q   + (size_t)NB*ND*4;
static const size_t OFF_WPH = OFF_OP  + (size_t)NB*32*ND*4;
static const size_t OFF_WPL = OFF_WPH + (size_t)1280*ND*2;
static const size_t OFF_SC  = OFF_WPL + (size_t)1280*ND*2;
static const size_t OFF_SH  = OFF_SC  + (size_t)ND*4;
static const size_t OFF_HA  = OFF_SH  + (size_t)ND*4;        // halted buf A [NB]
static const size_t OFF_HB  = OFF_HA  + 128;                 // halted buf B [NB]
static const size_t OFF_ZP  = OFF_HB  + 128;                 // 128B zero pad (16B aligned)

__device__ __forceinline__ float uh2f(ushort u) {
    _Float16 h = __builtin_bit_cast(_Float16, u);
    return (float)h;
}
__device__ __forceinline__ ushort f2uh(float f) {
    _Float16 h = (_Float16)f;
    return __builtin_bit_cast(ushort, h);
}
__device__ __forceinline__ void load_lds16(const void* g, void* l) {
    __builtin_amdgcn_global_load_lds((const __attribute__((address_space(1))) void*)g,
                                     (__attribute__((address_space(3))) void*)l, 16, 0, 0);
}

// ---------------- split fp32 x -> (hi, lo) f16 planes ----------------
__global__ void k_split(const float* __restrict__ x, ushort* __restrict__ hi, ushort* __restrict__ lo)
{
    size_t i = ((size_t)blockIdx.x * 256 + threadIdx.x) * 4;
    float4 v = *(const float4*)(x + i);
    ushort4 h, l;
    h.x = f2uh(v.x); l.x = f2uh(v.x - uh2f(h.x));
    h.y = f2uh(v.y); l.y = f2uh(v.y - uh2f(h.y));
    h.z = f2uh(v.z); l.z = f2uh(v.z - uh2f(h.z));
    h.w = f2uh(v.w); l.w = f2uh(v.w - uh2f(h.w));
    *(ushort4*)(hi + i) = h;
    *(ushort4*)(lo + i) = l;
}

// ---------------- init: pack W (hi/lo), BN affine, q, halted bufs, zpad ----------------
// W layout: idx = ((((kc*5 + t)*2 + ds)*256 + dout)*4 + kl)*8 + dj
//   where din = kc*64 + ds*32 + kl*8 + dj.  n-fragment stride (dout += 16) = 512 elem = 1024 B.
__global__ void k_init(const float* __restrict__ conv_w, const float* __restrict__ conv_b,
                       const float* __restrict__ bn_gamma, const float* __restrict__ bn_beta,
                       const float* __restrict__ bn_mean, const float* __restrict__ bn_var,
                       const float* __restrict__ query,
                       ushort* __restrict__ Wph, ushort* __restrict__ Wpl,
                       float* __restrict__ scale, float* __restrict__ shift,
                       float* __restrict__ q, int* __restrict__ hA, int* __restrict__ hB,
                       ushort* __restrict__ zpad)
{
    int idx = blockIdx.x * 256 + threadIdx.x;
    if (idx < 1280 * 256) {
        int dj   = idx & 7;
        int kl   = (idx >> 3) & 3;
        int dout = (idx >> 5) & 255;
        int rest = idx >> 13;            // 0..39 = (kc*5 + t)*2 + ds
        int ds_  = rest & 1;
        int tkc  = rest >> 1;            // kc*5 + t
        int t    = tkc % 5;
        int kc   = tkc / 5;
        int din  = kc * 64 + ds_ * 32 + kl * 8 + dj;
        float w = conv_w[dout * 1280 + din * 5 + t];
        ushort wh = f2uh(w);
        Wph[idx] = wh;
        Wpl[idx] = f2uh(w - uh2f(wh));
    }
    if (idx < NB * ND) q[idx] = query[idx & (ND - 1)];
    if (idx < ND) {
        float a = bn_gamma[idx] * rsqrtf(bn_var[idx] + EPSBN);
        scale[idx] = a;
        shift[idx] = (conv_b[idx] - bn_mean[idx]) * a + bn_beta[idx];
    }
    if (idx < 128) zpad[idx] = 0;
    if (idx < NB) { hA[idx] = 0; hB[idx] = 0; }
}

// ---------------- K3: conv + attention-e + flash softmax partials ----------------
// block 256 thr = 4 waves; tile 128 rows x 256 douts; wave = 128 rows x 64 douts
// (M_rep=8, N_rep=4 of 16x16x32).  128 VGPR + 128 AGPR operating point.
// KEY SCHEDULING FIX: STAGE of the next kc-chunk is split into 5 parts issued inside
// td-steps 0..4 AFTER each step's B-frag loads.  vmcnt is a FIFO — issuing all STAGE
// loads up-front made every early-td B-frag wait drain the whole 131KB stage.  Now any
// B-wait is at most ~1 td-step deep.  No arithmetic change (absmax must be identical).
__global__ __launch_bounds__(256, 2) void k_conv(
    const ushort* __restrict__ xhi, const ushort* __restrict__ xlo,
    ushort* __restrict__ ohi, ushort* __restrict__ olo,
    const ushort* __restrict__ Wph, const ushort* __restrict__ Wpl,
    const float* __restrict__ scale, const float* __restrict__ shift,
    const int* __restrict__ maskp, const float* __restrict__ q,
    float* __restrict__ o_part, float* __restrict__ m_part, float* __restrict__ l_part,
    const ushort* __restrict__ zpad, const int* __restrict__ halted)
{
    const int bb  = blockIdx.x >> 5;
    const int s0  = (blockIdx.x & 31) << 7;
    const int tid = threadIdx.x;
    const int lane  = tid & 63;

    // running = !any(halted) (halted is read-only this dispatch -> no race)
    {
        int hv = (lane < NB) ? halted[lane] : 0;
        unsigned long long bl = __ballot(hv != 0);
        if (bl != 0ull) {   // frozen: copy state
            const size_t base = ((size_t)bb * NS + s0) * ND;
            const uint4* sh_ = (const uint4*)(xhi + base);
            const uint4* sl_ = (const uint4*)(xlo + base);
            uint4* dh = (uint4*)(ohi + base);
            uint4* dl = (uint4*)(olo + base);
            for (int i = tid; i < 4096; i += 256) { dh[i] = sh_[i]; dl[i] = sl_[i]; }
            return;
        }
    }

    // dbuf: [buf][Ah 17408B | Al 17408B]; 136 rows x 64 din per plane
    __shared__ __align__(16) char ldsA[2 * 34816];
    __shared__ float p_lds[128];
    __shared__ float red[128];
    __shared__ float s_mblk, s_lsum;

    const int wid   = tid >> 6;
    const int mlane = lane & 15;       // C col / A row lane
    const int klane = lane >> 4;       // k-block
    const int dbase = wid << 6;        // wave's dout base

    // e-dot ownership: 2 threads per row; esub=0 -> groups 0..3, esub=1 -> groups 4..7
    const int erow = tid >> 1;         // 0..127
    const int esub = tid & 1;
    const int elrow = erow + 2;        // LDS row
    const int ers = elrow & 7;         // staging swizzle key
    const int msk_row = maskp[bb * NS + s0 + erow];
    float ea0 = 0.f, ea1 = 0.f, ea2 = 0.f, ea3 = 0.f;   // 4 independent chains

    floatx4 acc[8][4];
    #pragma unroll
    for (int m = 0; m < 8; ++m)
        #pragma unroll
        for (int n = 0; n < 4; ++n) acc[m][n] = (floatx4){0.f, 0.f, 0.f, 0.f};

    // lane-fixed element offset within a (kc,td) W slab
    const int laneoff = (dbase + mlane) * 32 + klane * 8;

    // one part = 256 of the 1088 stage iterations (part 4: only tid<64)
    auto STAGE_PART = [&](int buf, int kc, int part) {
        char* bh_ = ldsA + (size_t)buf * 34816;
        char* bl_ = bh_ + 17408;
        int i0 = tid + (part << 8);
        if (i0 < 1088) {
            int lrow = i0 >> 3;
            int grp  = (i0 & 7) ^ (lrow & 7);
            int srow = s0 - 2 + lrow;
            const ushort* ph;
            const ushort* pl;
            if (srow >= 0 && srow < NS) {
                size_t go = ((size_t)bb * NS + srow) * ND + (kc << 6) + (grp << 3);
                ph = xhi + go; pl = xlo + go;
            } else {
                ph = zpad + (grp << 3); pl = zpad + (grp << 3);
            }
            load_lds16(ph, bh_ + i0 * 16);
            load_lds16(pl, bl_ + i0 * 16);
        }
    };

    // prologue: stage chunk 0 (all parts), preload B-frags for X=0
    #pragma unroll
    for (int p = 0; p < 5; ++p) STAGE_PART(0, 0, p);
    half8 bh[4], bl[4], nbh[4], nbl[4];
    {
        const ushort* wb = Wph + laneoff;
        const ushort* wc = Wpl + laneoff;
        #pragma unroll
        for (int n = 0; n < 4; ++n) {
            bh[n] = *(const half8*)(wb + n * 512);
            bl[n] = *(const half8*)(wc + n * 512);
        }
    }
    asm volatile("s_waitcnt vmcnt(0) lgkmcnt(0)" ::: "memory");
    __builtin_amdgcn_s_barrier();
    asm volatile("" ::: "memory");

    for (int kc = 0; kc < 4; ++kc) {
        const int cur = kc & 1;
        const char* Ah = ldsA + cur * 34816;
        const char* Al = Ah + 17408;

        // ---- attention dot for this chunk: 4 ILP chains (reads current buffer) ----
        if (!msk_row) {
            const float* qb = q + bb * ND + (kc << 6);
            int off0 = (elrow << 7) + ((((esub << 2) + 0) ^ ers) << 4);
            int off1 = (elrow << 7) + ((((esub << 2) + 1) ^ ers) << 4);
            int off2 = (elrow << 7) + ((((esub << 2) + 2) ^ ers) << 4);
            int off3 = (elrow << 7) + ((((esub << 2) + 3) ^ ers) << 4);
            half8 h0 = *(const half8*)(Ah + off0), l0 = *(const half8*)(Al + off0);
            half8 h1 = *(const half8*)(Ah + off1), l1 = *(const half8*)(Al + off1);
            half8 h2 = *(const half8*)(Ah + off2), l2 = *(const half8*)(Al + off2);
            half8 h3 = *(const half8*)(Ah + off3), l3 = *(const half8*)(Al + off3);
            const float* q0p = qb + (((esub << 2) + 0) << 3);
            const float* q1p = qb + (((esub << 2) + 1) << 3);
            const float* q2p = qb + (((esub << 2) + 2) << 3);
            const float* q3p = qb + (((esub << 2) + 3) << 3);
            #pragma unroll
            for (int j = 0; j < 8; ++j) {
                ea0 += ((float)h0[j] + (float)l0[j]) * q0p[j];
                ea1 += ((float)h1[j] + (float)l1[j]) * q1p[j];
                ea2 += ((float)h2[j] + (float)l2[j]) * q2p[j];
                ea3 += ((float)h3[j] + (float)l3[j]) * q3p[j];
            }
        }

        #pragma unroll
        for (int td = 0; td < 10; ++td) {     // td = t*2 + ds_
            const int X = kc * 10 + td;
            // ---- issue B-frag loads for step X+1 (land during this step's MFMAs) ----
            {
                const int Xn = (X < 39) ? X + 1 : 39;
                const ushort* wb = Wph + (size_t)Xn * 8192 + laneoff;
                const ushort* wc = Wpl + (size_t)Xn * 8192 + laneoff;
                #pragma unroll
                for (int n = 0; n < 4; ++n) {
                    nbh[n] = *(const half8*)(wb + n * 512);
                    nbl[n] = *(const half8*)(wc + n * 512);
                }
            }
            // ---- chunked STAGE of next kc: one part per td-step 0..4, issued AFTER
            //      the B-frag loads so B-waits never drain the stage FIFO ----
            if (kc < 3 && td < 5) STAGE_PART(cur ^ 1, kc + 1, td);

            const int t   = td >> 1;
            const int ds_ = td & 1;
            const int gb  = (ds_ << 2) + klane;   // 16B group within 64-din row

            __builtin_amdgcn_s_setprio(1);
            #pragma unroll
            for (int m = 0; m < 8; ++m) {
                int row = (m << 4) + mlane + t;      // lds row = out_row + t
                int off = (row << 7) + ((gb ^ (row & 7)) << 4);
                half8 ah = *(const half8*)(Ah + off);
                half8 al = *(const half8*)(Al + off);
                #pragma unroll
                for (int n = 0; n < 4; ++n)
                    acc[m][n] = __builtin_amdgcn_mfma_f32_16x16x32_f16(ah, bh[n], acc[m][n], 0, 0, 0);
                #pragma unroll
                for (int n = 0; n < 4; ++n)
                    acc[m][n] = __builtin_amdgcn_mfma_f32_16x16x32_f16(ah, bl[n], acc[m][n], 0, 0, 0);
                #pragma unroll
                for (int n = 0; n < 4; ++n)
                    acc[m][n] = __builtin_amdgcn_mfma_f32_16x16x32_f16(al, bh[n], acc[m][n], 0, 0, 0);
            }
            __builtin_amdgcn_s_setprio(0);

            // rotate pipelined B-frags
            #pragma unroll
            for (int n = 0; n < 4; ++n) { bh[n] = nbh[n]; bl[n] = nbl[n]; }
        }

        if (kc < 3) {   // flip buffers; nothing to protect after the last chunk
            asm volatile("s_waitcnt vmcnt(0) lgkmcnt(0)" ::: "memory");
            __builtin_amdgcn_s_barrier();
            asm volatile("" ::: "memory");
        }
    }

    // ---- collapse chains, combine row halves, block-local softmax ----
    float e_acc = (ea0 + ea1) + (ea2 + ea3);
    e_acc += __shfl_xor(e_acc, 1, 64);
    if (esub == 0) red[erow] = msk_row ? -INFINITY : e_acc;
    __syncthreads();
    if (tid < 64) {
        float v = fmaxf(red[tid], red[tid + 64]);
        #pragma unroll
        for (int off = 32; off; off >>= 1) v = fmaxf(v, __shfl_xor(v, off, 64));
        if (tid == 0) s_mblk = v;
    }
    __syncthreads();
    const float mb = s_mblk;
    if (tid < 128) {
        float pt = expf(red[tid] - mb);   // -inf -> 0
        p_lds[tid] = pt;
    }
    __syncthreads();
    if (tid < 64) {
        float v = p_lds[tid] + p_lds[tid + 64];
        #pragma unroll
        for (int off = 32; off; off >>= 1) v += __shfl_xor(v, off, 64);
        if (tid == 0) s_lsum = v;
    }
    __syncthreads();
    if (tid == 0) {
        m_part[bb * 32 + (s0 >> 7)] = mb;
        l_part[bb * 32 + (s0 >> 7)] = s_lsum;
    }

    // epilogue: BN + leakyReLU + mask, emit split f16, fused (unnormalized) o partials
    float sc[4], sh[4];
    #pragma unroll
    for (int n = 0; n < 4; ++n) {
        int d = dbase + (n << 4) + mlane;
        sc[n] = scale[d]; sh[n] = shift[d];
    }
    float osum[4] = {0.f, 0.f, 0.f, 0.f};
    #pragma unroll
    for (int m = 0; m < 8; ++m) {
        #pragma unroll
        for (int r = 0; r < 4; ++r) {
            int prow = (m << 4) + (klane << 2) + r;  // C/D: row=(lane>>4)*4+reg
            int s = s0 + prow;
            int mk = maskp[bb * NS + s];
            float po = p_lds[prow];
            size_t ob = ((size_t)bb * NS + s) * ND + dbase + mlane;
            #pragma unroll
            for (int n = 0; n < 4; ++n) {
                float v = acc[m][n][r] * sc[n] + sh[n];
                v = (v >= 0.f) ? v : NEG_SLOPE * v;
                v = mk ? 0.f : v;
                ushort hw = f2uh(v);
                ushort lw = f2uh(v - uh2f(hw));
                ohi[ob + (size_t)(n << 4)] = hw;
                olo[ob + (size_t)(n << 4)] = lw;
                osum[n] += po * v;
            }
        }
    }
    #pragma unroll
    for (int n = 0; n < 4; ++n) {
        osum[n] += __shfl_xor(osum[n], 16, 64);
        osum[n] += __shfl_xor(osum[n], 32, 64);
    }
    if (lane < 16) {
        float* op = o_part + ((size_t)bb * 32 + (s0 >> 7)) * ND;
        #pragma unroll
        for (int n = 0; n < 4; ++n)
            op[dbase + (n << 4) + mlane] = osum[n];
    }
}

// ---------------- K5: flash combine o, halt logits, gated q update ----------------
// Reads hIn (previous hop's halted state), writes hOut — no intra-dispatch race.
__global__ void k_update(const float* __restrict__ o_part, const float* __restrict__ m_part,
                         const float* __restrict__ l_part, float* __restrict__ q,
                         const float* __restrict__ halt_w, const float* __restrict__ halt_b,
                         const int* __restrict__ hIn, int* __restrict__ hOut)
{
    int b = blockIdx.x, d = threadIdx.x;
    int lane = d & 63;
    // running = !any(halted) BEFORE this step's update
    int hv = (lane < NB) ? hIn[lane] : 0;
    unsigned long long bl = __ballot(hv != 0);
    int running = (bl == 0ull) ? 1 : 0;

    __shared__ float w[33];
    __shared__ float sh0[256], sh1[256];
    if (d == 0) {
        float M = -INFINITY;
        for (int ch = 0; ch < 32; ++ch) M = fmaxf(M, m_part[b * 32 + ch]);
        float S = 0.f;
        for (int ch = 0; ch < 32; ++ch) {
            float wv = expf(m_part[b * 32 + ch] - M);
            w[ch] = wv;
            S += wv * l_part[b * 32 + ch];
        }
        w[32] = 1.0f / S;
    }
    __syncthreads();
    float o = 0.f;
    #pragma unroll
    for (int ch = 0; ch < 32; ++ch) o += w[ch] * o_part[(b * 32 + ch) * ND + d];
    o *= w[32];

    float qd = q[b * ND + d];
    float s1 = o + qd;
    sh0[d] = s1 * halt_w[d];
    sh1[d] = s1 * halt_w[ND + d];
    __syncthreads();
    for (int off = 128; off; off >>= 1) {
        if (d < off) { sh0[d] += sh0[d + off]; sh1[d] += sh1[d + off]; }
        __syncthreads();
    }
    float l0 = sh0[0] + halt_b[0];
    float l1 = sh1[0] + halt_b[1];
    int hOld = hIn[b];
    if (running) {
        q[b * ND + d] = o + qd * (1.f - (float)hOld);
        if (d == 0) hOut[b] = hOld | ((l1 > l0) ? 1 : 0);
    } else {
        if (d == 0) hOut[b] = hOld;
    }
}

// ---------------- K6: q -> d_out ----------------
__global__ void k_copyout(const float* __restrict__ q, float* __restrict__ out)
{
    int idx = blockIdx.x * 256 + threadIdx.x;
    if (idx < NB * ND) out[idx] = q[idx];
}

extern "C" void kernel_launch(void* const* d_in, const int* in_sizes, int n_in,
                              void* d_out, int out_size, void* d_ws, size_t ws_size,
                              hipStream_t stream)
{
    const float* x        = (const float*)d_in[0];
    const int*   mask     = (const int*)  d_in[1];
    const float* query    = (const float*)d_in[2];
    const float* conv_w   = (const float*)d_in[3];
    const float* conv_b   = (const float*)d_in[4];
    const float* bn_gamma = (const float*)d_in[5];
    const float* bn_beta  = (const float*)d_in[6];
    const float* bn_mean  = (const float*)d_in[7];
    const float* bn_var   = (const float*)d_in[8];
    const float* halt_w   = (const float*)d_in[9];
    const float* halt_b   = (const float*)d_in[10];

    char* ws = (char*)d_ws;
    ushort* hi0 = (ushort*)(ws + OFF_HI0);
    ushort* lo0 = (ushort*)(ws + OFF_LO0);
    ushort* hi1 = (ushort*)(ws + OFF_HI1);
    ushort* lo1 = (ushort*)(ws + OFF_LO1);
    float* mpart= (float*)(ws + OFF_MP);
    float* lpart= (float*)(ws + OFF_LP);
    float* qbuf = (float*)(ws + OFF_Q);
    float* opart= (float*)(ws + OFF_OP);
    ushort* Wph = (ushort*)(ws + OFF_WPH);
    ushort* Wpl = (ushort*)(ws + OFF_WPL);
    float* scale= (float*)(ws + OFF_SC);
    float* shift= (float*)(ws + OFF_SH);
    int* hA     = (int*)  (ws + OFF_HA);
    int* hB     = (int*)  (ws + OFF_HB);
    ushort* zpad= (ushort*)(ws + OFF_ZP);

    k_init<<<1280, 256, 0, stream>>>(conv_w, conv_b, bn_gamma, bn_beta, bn_mean, bn_var,
                                     query, Wph, Wpl, scale, shift, qbuf, hA, hB, zpad);
    k_split<<<32768, 256, 0, stream>>>(x, hi0, lo0);

    for (int h = 0; h < NHOP; ++h) {
        const ushort* ih = (h & 1) ? hi1 : hi0;
        const ushort* il = (h & 1) ? lo1 : lo0;
        ushort* oh = (h & 1) ? hi0 : hi1;
        ushort* ol = (h & 1) ? lo0 : lo1;
        const int* hIn = (h & 1) ? hB : hA;
        int*       hOut= (h & 1) ? hA : hB;

        k_conv  <<<NB * 32, 256, 0, stream>>>(ih, il, oh, ol, Wph, Wpl, scale, shift,
                                              mask, qbuf, opart, mpart, lpart, zpad, hIn);
        k_update<<<NB, 256, 0, stream>>>(opart, mpart, lpart, qbuf, halt_w, halt_b, hIn, hOut);
    }

    k_copyout<<<NB, 256, 0, stream>>>(qbuf, (float*)d_out);
}

// Round 13
// 2037.762 us; speedup vs baseline: 1.2582x; 1.2582x over previous
//
#include <hip/hip_runtime.h>
#include <hip/hip_bf16.h>
#include <math.h>

#define NB 32
#define NS 4096
#define ND 256
#define NHOP 10
#define EPSBN 1e-5f
#define NEG_SLOPE 0.01f

typedef _Float16 half8 __attribute__((ext_vector_type(8)));
typedef float floatx4 __attribute__((ext_vector_type(4)));

// ---------------- workspace layout (bytes) ----------------
static const size_t SZ_PAIR = (size_t)NB*NS*ND*2;            // 67,108,864 (ushort plane)
static const size_t OFF_HI0 = 0;
static const size_t OFF_LO0 = OFF_HI0 + SZ_PAIR;
static const size_t OFF_HI1 = OFF_LO0 + SZ_PAIR;
static const size_t OFF_LO1 = OFF_HI1 + SZ_PAIR;
static const size_t OFF_MP  = OFF_LO1 + SZ_PAIR;             // m_part [NB*32]
static const size_t OFF_LP  = OFF_MP  + (size_t)NB*32*4;     // l_part [NB*32]
static const size_t OFF_Q   = OFF_LP  + (size_t)NB*32*4;
static const size_t OFF_OP  = OFF_Q   + (size_t)NB*ND*4;
static const size_t OFF_WPH = OFF_OP  + (size_t)NB*32*ND*4;
static const size_t OFF_WPL = OFF_WPH + (size_t)1280*ND*2;
static const size_t OFF_SC  = OFF_WPL + (size_t)1280*ND*2;
static const size_t OFF_SH  = OFF_SC  + (size_t)ND*4;
static const size_t OFF_HA  = OFF_SH  + (size_t)ND*4;        // halted buf A [NB]
static const size_t OFF_HB  = OFF_HA  + 128;                 // halted buf B [NB]
static const size_t OFF_ZP  = OFF_HB  + 128;                 // 128B zero pad (16B aligned)

__device__ __forceinline__ float uh2f(ushort u) {
    _Float16 h = __builtin_bit_cast(_Float16, u);
    return (float)h;
}
__device__ __forceinline__ ushort f2uh(float f) {
    _Float16 h = (_Float16)f;
    return __builtin_bit_cast(ushort, h);
}
__device__ __forceinline__ void load_lds16(const void* g, void* l) {
    __builtin_amdgcn_global_load_lds((const __attribute__((address_space(1))) void*)g,
                                     (__attribute__((address_space(3))) void*)l, 16, 0, 0);
}

// ---------------- split fp32 x -> (hi, lo) f16 planes ----------------
__global__ void k_split(const float* __restrict__ x, ushort* __restrict__ hi, ushort* __restrict__ lo)
{
    size_t i = ((size_t)blockIdx.x * 256 + threadIdx.x) * 4;
    float4 v = *(const float4*)(x + i);
    ushort4 h, l;
    h.x = f2uh(v.x); l.x = f2uh(v.x - uh2f(h.x));
    h.y = f2uh(v.y); l.y = f2uh(v.y - uh2f(h.y));
    h.z = f2uh(v.z); l.z = f2uh(v.z - uh2f(h.z));
    h.w = f2uh(v.w); l.w = f2uh(v.w - uh2f(h.w));
    *(ushort4*)(hi + i) = h;
    *(ushort4*)(lo + i) = l;
}

// ---------------- init: pack W (hi/lo), BN affine, q, halted bufs, zpad ----------------
// W layout: idx = ((((kc*5 + t)*2 + ds)*256 + dout)*4 + kl)*8 + dj
//   where din = kc*64 + ds*32 + kl*8 + dj.  n-fragment stride (dout += 16) = 512 elem = 1024 B.
__global__ void k_init(const float* __restrict__ conv_w, const float* __restrict__ conv_b,
                       const float* __restrict__ bn_gamma, const float* __restrict__ bn_beta,
                       const float* __restrict__ bn_mean, const float* __restrict__ bn_var,
                       const float* __restrict__ query,
                       ushort* __restrict__ Wph, ushort* __restrict__ Wpl,
                       float* __restrict__ scale, float* __restrict__ shift,
                       float* __restrict__ q, int* __restrict__ hA, int* __restrict__ hB,
                       ushort* __restrict__ zpad)
{
    int idx = blockIdx.x * 256 + threadIdx.x;
    if (idx < 1280 * 256) {
        int dj   = idx & 7;
        int kl   = (idx >> 3) & 3;
        int dout = (idx >> 5) & 255;
        int rest = idx >> 13;            // 0..39 = (kc*5 + t)*2 + ds
        int ds_  = rest & 1;
        int tkc  = rest >> 1;            // kc*5 + t
        int t    = tkc % 5;
        int kc   = tkc / 5;
        int din  = kc * 64 + ds_ * 32 + kl * 8 + dj;
        float w = conv_w[dout * 1280 + din * 5 + t];
        ushort wh = f2uh(w);
        Wph[idx] = wh;
        Wpl[idx] = f2uh(w - uh2f(wh));
    }
    if (idx < NB * ND) q[idx] = query[idx & (ND - 1)];
    if (idx < ND) {
        float a = bn_gamma[idx] * rsqrtf(bn_var[idx] + EPSBN);
        scale[idx] = a;
        shift[idx] = (conv_b[idx] - bn_mean[idx]) * a + bn_beta[idx];
    }
    if (idx < 128) zpad[idx] = 0;
    if (idx < NB) { hA[idx] = 0; hB[idx] = 0; }
}

// ---------------- K3: conv + inline attention-e + flash softmax partials -------------------
// block 256 thr = 4 waves; tile 128 rows x 256 douts; wave = 128 rows x 64 douts
// (M_rep=8, N_rep=4 of 16x16x32).  128 VGPR + 128 AGPR operating point — AT THE REGISTER
// WALL: any added in-loop scheduling state spills (verified R4/R5/R10/R12).  Structure =
// round-9 empirical best; only change: final kc's dead vmcnt+barrier elided (kc<3 guard).
__global__ __launch_bounds__(256, 2) void k_conv(
    const ushort* __restrict__ xhi, const ushort* __restrict__ xlo,
    ushort* __restrict__ ohi, ushort* __restrict__ olo,
    const ushort* __restrict__ Wph, const ushort* __restrict__ Wpl,
    const float* __restrict__ scale, const float* __restrict__ shift,
    const int* __restrict__ maskp, const float* __restrict__ q,
    float* __restrict__ o_part, float* __restrict__ m_part, float* __restrict__ l_part,
    const ushort* __restrict__ zpad, const int* __restrict__ halted)
{
    const int bb  = blockIdx.x >> 5;
    const int s0  = (blockIdx.x & 31) << 7;
    const int tid = threadIdx.x;
    const int lane  = tid & 63;

    // running = !any(halted), computed per-wave (halted is read-only this dispatch)
    {
        int hv = (lane < NB) ? halted[lane] : 0;
        unsigned long long bl = __ballot(hv != 0);
        if (bl != 0ull) {   // frozen: copy state
            const size_t base = ((size_t)bb * NS + s0) * ND;
            const uint4* sh_ = (const uint4*)(xhi + base);
            const uint4* sl_ = (const uint4*)(xlo + base);
            uint4* dh = (uint4*)(ohi + base);
            uint4* dl = (uint4*)(olo + base);
            for (int i = tid; i < 4096; i += 256) { dh[i] = sh_[i]; dl[i] = sl_[i]; }
            return;
        }
    }

    // dbuf: [buf][Ah 17408B | Al 17408B]; 136 rows x 64 din per plane
    __shared__ __align__(16) char ldsA[2 * 34816];
    __shared__ float p_lds[128];
    __shared__ float red[128];
    __shared__ float s_mblk, s_lsum;

    const int wid   = tid >> 6;
    const int mlane = lane & 15;       // C col / A row lane
    const int klane = lane >> 4;       // k-block
    const int dbase = wid << 6;        // wave's dout base

    // per-row mask + e accumulator (rows owned by tid<128)
    const int msk_row = (tid < 128) ? maskp[bb * NS + s0 + tid] : 1;
    float e_acc = 0.f;

    floatx4 acc[8][4];
    #pragma unroll
    for (int m = 0; m < 8; ++m)
        #pragma unroll
        for (int n = 0; n < 4; ++n) acc[m][n] = (floatx4){0.f, 0.f, 0.f, 0.f};

    // lane-fixed element offset within a (kc,td) W slab
    const int laneoff = (dbase + mlane) * 32 + klane * 8;

    auto STAGE = [&](int buf, int kc) {
        char* bh_ = ldsA + (size_t)buf * 34816;
        char* bl_ = bh_ + 17408;
        for (int i0 = tid; i0 < 1088; i0 += 256) {
            int lrow = i0 >> 3;
            int grp  = (i0 & 7) ^ (lrow & 7);
            int srow = s0 - 2 + lrow;
            const ushort* ph;
            const ushort* pl;
            if (srow >= 0 && srow < NS) {
                size_t go = ((size_t)bb * NS + srow) * ND + (kc << 6) + (grp << 3);
                ph = xhi + go; pl = xlo + go;
            } else {
                ph = zpad + (grp << 3); pl = zpad + (grp << 3);
            }
            load_lds16(ph, bh_ + i0 * 16);
            load_lds16(pl, bl_ + i0 * 16);
        }
    };

    // prologue: stage chunk 0, preload B-frags for X=0
    STAGE(0, 0);
    half8 bh[4], bl[4], nbh[4], nbl[4];
    {
        const ushort* wb = Wph + laneoff;
        const ushort* wc = Wpl + laneoff;
        #pragma unroll
        for (int n = 0; n < 4; ++n) {
            bh[n] = *(const half8*)(wb + n * 512);
            bl[n] = *(const half8*)(wc + n * 512);
        }
    }
    asm volatile("s_waitcnt vmcnt(0) lgkmcnt(0)" ::: "memory");
    __builtin_amdgcn_s_barrier();
    asm volatile("" ::: "memory");

    for (int kc = 0; kc < 4; ++kc) {
        const int cur = kc & 1;
        if (kc < 3) STAGE(cur ^ 1, kc + 1);   // prefetch next chunk into other buffer

        const char* Ah = ldsA + cur * 34816;
        const char* Al = Ah + 17408;

        // ---- inline attention dot for this chunk: e_row += x[row, kc*64..+64] . q ----
        if (tid < 128 && !msk_row) {
            const int lrow = tid + 2;
            const int rs = lrow & 7;
            const float* qp = q + bb * ND + (kc << 6);
            float ea = 0.f;
            #pragma unroll
            for (int g = 0; g < 8; ++g) {
                int off = (lrow << 7) + ((g ^ rs) << 4);
                half8 hh = *(const half8*)(Ah + off);
                half8 ll = *(const half8*)(Al + off);
                float4 q0 = *(const float4*)(qp + g * 8);
                float4 q1 = *(const float4*)(qp + g * 8 + 4);
                ea += ((float)hh[0] + (float)ll[0]) * q0.x;
                ea += ((float)hh[1] + (float)ll[1]) * q0.y;
                ea += ((float)hh[2] + (float)ll[2]) * q0.z;
                ea += ((float)hh[3] + (float)ll[3]) * q0.w;
                ea += ((float)hh[4] + (float)ll[4]) * q1.x;
                ea += ((float)hh[5] + (float)ll[5]) * q1.y;
                ea += ((float)hh[6] + (float)ll[6]) * q1.z;
                ea += ((float)hh[7] + (float)ll[7]) * q1.w;
            }
            e_acc += ea;
        }

        #pragma unroll
        for (int td = 0; td < 10; ++td) {     // td = t*2 + ds_
            const int X = kc * 10 + td;
            // ---- issue B-frag loads for step X+1 (land during this step's MFMAs) ----
            {
                const int Xn = (X < 39) ? X + 1 : 39;
                const ushort* wb = Wph + (size_t)Xn * 8192 + laneoff;
                const ushort* wc = Wpl + (size_t)Xn * 8192 + laneoff;
                #pragma unroll
                for (int n = 0; n < 4; ++n) {
                    nbh[n] = *(const half8*)(wb + n * 512);
                    nbl[n] = *(const half8*)(wc + n * 512);
                }
            }
            const int t   = td >> 1;
            const int ds_ = td & 1;
            const int gb  = (ds_ << 2) + klane;   // 16B group within 64-din row

            __builtin_amdgcn_s_setprio(1);
            #pragma unroll
            for (int m = 0; m < 8; ++m) {
                int row = (m << 4) + mlane + t;      // lds row = out_row + t
                int off = (row << 7) + ((gb ^ (row & 7)) << 4);
                half8 ah = *(const half8*)(Ah + off);
                half8 al = *(const half8*)(Al + off);
                #pragma unroll
                for (int n = 0; n < 4; ++n)
                    acc[m][n] = __builtin_amdgcn_mfma_f32_16x16x32_f16(ah, bh[n], acc[m][n], 0, 0, 0);
                #pragma unroll
                for (int n = 0; n < 4; ++n)
                    acc[m][n] = __builtin_amdgcn_mfma_f32_16x16x32_f16(ah, bl[n], acc[m][n], 0, 0, 0);
                #pragma unroll
                for (int n = 0; n < 4; ++n)
                    acc[m][n] = __builtin_amdgcn_mfma_f32_16x16x32_f16(al, bh[n], acc[m][n], 0, 0, 0);
            }
            __builtin_amdgcn_s_setprio(0);

            // rotate pipelined B-frags
            #pragma unroll
            for (int n = 0; n < 4; ++n) { bh[n] = nbh[n]; bl[n] = nbl[n]; }
        }

        if (kc < 3) {   // flip buffers; final kc's drain is subsumed by softmax's syncthreads
            asm volatile("s_waitcnt vmcnt(0) lgkmcnt(0)" ::: "memory");
            __builtin_amdgcn_s_barrier();
            asm volatile("" ::: "memory");
        }
    }

    // ---- block-local softmax: m_blk = max(e), p~ = exp(e - m_blk), L~ = sum(p~) ----
    if (tid < 128) red[tid] = msk_row ? -INFINITY : e_acc;
    __syncthreads();
    if (tid < 64) {
        float v = fmaxf(red[tid], red[tid + 64]);
        #pragma unroll
        for (int off = 32; off; off >>= 1) v = fmaxf(v, __shfl_xor(v, off, 64));
        if (tid == 0) s_mblk = v;
    }
    __syncthreads();
    const float mb = s_mblk;
    if (tid < 128) {
        float pt = msk_row ? 0.f : expf(e_acc - mb);
        p_lds[tid] = pt;
        red[tid] = pt;
    }
    __syncthreads();
    if (tid < 64) {
        float v = red[tid] + red[tid + 64];
        #pragma unroll
        for (int off = 32; off; off >>= 1) v += __shfl_xor(v, off, 64);
        if (tid == 0) s_lsum = v;
    }
    __syncthreads();
    if (tid == 0) {
        m_part[bb * 32 + (s0 >> 7)] = mb;
        l_part[bb * 32 + (s0 >> 7)] = s_lsum;
    }

    // epilogue: BN + leakyReLU + mask, emit split f16, fused (unnormalized) o partials
    float sc[4], sh[4];
    #pragma unroll
    for (int n = 0; n < 4; ++n) {
        int d = dbase + (n << 4) + mlane;
        sc[n] = scale[d]; sh[n] = shift[d];
    }
    float osum[4] = {0.f, 0.f, 0.f, 0.f};
    #pragma unroll
    for (int m = 0; m < 8; ++m) {
        #pragma unroll
        for (int r = 0; r < 4; ++r) {
            int prow = (m << 4) + (klane << 2) + r;  // C/D: row=(lane>>4)*4+reg
            int s = s0 + prow;
            int mk = maskp[bb * NS + s];
            float po = p_lds[prow];
            size_t ob = ((size_t)bb * NS + s) * ND + dbase + mlane;
            #pragma unroll
            for (int n = 0; n < 4; ++n) {
                float v = acc[m][n][r] * sc[n] + sh[n];
                v = (v >= 0.f) ? v : NEG_SLOPE * v;
                v = mk ? 0.f : v;
                ushort hw = f2uh(v);
                ushort lw = f2uh(v - uh2f(hw));
                ohi[ob + (size_t)(n << 4)] = hw;
                olo[ob + (size_t)(n << 4)] = lw;
                osum[n] += po * v;
            }
        }
    }
    #pragma unroll
    for (int n = 0; n < 4; ++n) {
        osum[n] += __shfl_xor(osum[n], 16, 64);
        osum[n] += __shfl_xor(osum[n], 32, 64);
    }
    if (lane < 16) {
        float* op = o_part + ((size_t)bb * 32 + (s0 >> 7)) * ND;
        #pragma unroll
        for (int n = 0; n < 4; ++n)
            op[dbase + (n << 4) + mlane] = osum[n];
    }
}

// ---------------- K5: flash combine o, halt logits, gated q update ----------------
// Reads hIn (previous hop's halted state), writes hOut — no intra-dispatch race.
__global__ void k_update(const float* __restrict__ o_part, const float* __restrict__ m_part,
                         const float* __restrict__ l_part, float* __restrict__ q,
                         const float* __restrict__ halt_w, const float* __restrict__ halt_b,
                         const int* __restrict__ hIn, int* __restrict__ hOut)
{
    int b = blockIdx.x, d = threadIdx.x;
    int lane = d & 63;
    // running = !any(halted) BEFORE this step's update
    int hv = (lane < NB) ? hIn[lane] : 0;
    unsigned long long bl = __ballot(hv != 0);
    int running = (bl == 0ull) ? 1 : 0;

    __shared__ float w[33];
    __shared__ float sh0[256], sh1[256];
    if (d == 0) {
        float M = -INFINITY;
        for (int ch = 0; ch < 32; ++ch) M = fmaxf(M, m_part[b * 32 + ch]);
        float S = 0.f;
        for (int ch = 0; ch < 32; ++ch) {
            float wv = expf(m_part[b * 32 + ch] - M);
            w[ch] = wv;
            S += wv * l_part[b * 32 + ch];
        }
        w[32] = 1.0f / S;
    }
    __syncthreads();
    float o = 0.f;
    #pragma unroll
    for (int ch = 0; ch < 32; ++ch) o += w[ch] * o_part[(b * 32 + ch) * ND + d];
    o *= w[32];

    float qd = q[b * ND + d];
    float s1 = o + qd;
    sh0[d] = s1 * halt_w[d];
    sh1[d] = s1 * halt_w[ND + d];
    __syncthreads();
    for (int off = 128; off; off >>= 1) {
        if (d < off) { sh0[d] += sh0[d + off]; sh1[d] += sh1[d + off]; }
        __syncthreads();
    }
    float l0 = sh0[0] + halt_b[0];
    float l1 = sh1[0] + halt_b[1];
    int hOld = hIn[b];
    if (running) {
        q[b * ND + d] = o + qd * (1.f - (float)hOld);
        if (d == 0) hOut[b] = hOld | ((l1 > l0) ? 1 : 0);
    } else {
        if (d == 0) hOut[b] = hOld;
    }
}

// ---------------- K6: q -> d_out ----------------
__global__ void k_copyout(const float* __restrict__ q, float* __restrict__ out)
{
    int idx = blockIdx.x * 256 + threadIdx.x;
    if (idx < NB * ND) out[idx] = q[idx];
}

extern "C" void kernel_launch(void* const* d_in, const int* in_sizes, int n_in,
                              void* d_out, int out_size, void* d_ws, size_t ws_size,
                              hipStream_t stream)
{
    const float* x        = (const float*)d_in[0];
    const int*   mask     = (const int*)  d_in[1];
    const float* query    = (const float*)d_in[2];
    const float* conv_w   = (const float*)d_in[3];
    const float* conv_b   = (const float*)d_in[4];
    const float* bn_gamma = (const float*)d_in[5];
    const float* bn_beta  = (const float*)d_in[6];
    const float* bn_mean  = (const float*)d_in[7];
    const float* bn_var   = (const float*)d_in[8];
    const float* halt_w   = (const float*)d_in[9];
    const float* halt_b   = (const float*)d_in[10];

    char* ws = (char*)d_ws;
    ushort* hi0 = (ushort*)(ws + OFF_HI0);
    ushort* lo0 = (ushort*)(ws + OFF_LO0);
    ushort* hi1 = (ushort*)(ws + OFF_HI1);
    ushort* lo1 = (ushort*)(ws + OFF_LO1);
    float* mpart= (float*)(ws + OFF_MP);
    float* lpart= (float*)(ws + OFF_LP);
    float* qbuf = (float*)(ws + OFF_Q);
    float* opart= (float*)(ws + OFF_OP);
    ushort* Wph = (ushort*)(ws + OFF_WPH);
    ushort* Wpl = (ushort*)(ws + OFF_WPL);
    float* scale= (float*)(ws + OFF_SC);
    float* shift= (float*)(ws + OFF_SH);
    int* hA     = (int*)  (ws + OFF_HA);
    int* hB     = (int*)  (ws + OFF_HB);
    ushort* zpad= (ushort*)(ws + OFF_ZP);

    k_init<<<1280, 256, 0, stream>>>(conv_w, conv_b, bn_gamma, bn_beta, bn_mean, bn_var,
                                     query, Wph, Wpl, scale, shift, qbuf, hA, hB, zpad);
    k_split<<<32768, 256, 0, stream>>>(x, hi0, lo0);

    for (int h = 0; h < NHOP; ++h) {
        const ushort* ih = (h & 1) ? hi1 : hi0;
        const ushort* il = (h & 1) ? lo1 : lo0;
        ushort* oh = (h & 1) ? hi0 : hi1;
        ushort* ol = (h & 1) ? lo0 : lo1;
        const int* hIn = (h & 1) ? hB : hA;
        int*       hOut= (h & 1) ? hA : hB;

        k_conv  <<<NB * 32, 256, 0, stream>>>(ih, il, oh, ol, Wph, Wpl, scale, shift,
                                              mask, qbuf, opart, mpart, lpart, zpad, hIn);
        k_update<<<NB, 256, 0, stream>>>(opart, mpart, lpart, qbuf, halt_w, halt_b, hIn, hOut);
    }

    k_copyout<<<NB, 256, 0, stream>>>(qbuf, (float*)d_out);
}